// Round 13
// baseline (5111.954 us; speedup 1.0000x reference)
//
#include <hip/hip_runtime.h>
#include <stdint.h>
#include <stddef.h>

typedef __attribute__((ext_vector_type(8))) short short8;
typedef __attribute__((ext_vector_type(4))) float f32x4;

#define MFMA16(A, B, C) __builtin_amdgcn_mfma_f32_16x16x32_bf16((A), (B), (C), 0, 0, 0)

// ---------- workspace layout (bytes) ----------
static const size_t OFF_WIH  = 67108864;             // w_ih bf16   [4096, 1024]     8388608
static const size_t OFF_WHH  = 75497472;             // w_hh bf16   [4096, 1024]     8388608
static const size_t OFF_BIAS = 83886080;             // b_ih+b_hh   [4096] f32         16384
static const size_t OFF_H0   = 83902464;             // h buf 0 bf16 [64,1024]        131072
static const size_t OFF_H1   = 84033536;             // h buf 1 bf16                  131072
static const size_t OFF_FLG  = 84164608;             // u32[512]: sync ctr[0..255], xwprog[256..511]
static const size_t OFF_XW   = 84426752;             // xW [512*64, 4096] f32 or bf16
static const size_t XW_F32_BYTES = 536870912;

__device__ __forceinline__ unsigned short f2bf(float f) {
    union { float f; uint32_t u; } v; v.f = f;
    uint32_t u = v.u;
    u += 0x7FFFu + ((u >> 16) & 1u);   // round-to-nearest-even
    return (unsigned short)(u >> 16);
}
__device__ __forceinline__ float bf2f(unsigned short b) {
    union { uint32_t u; float f; } v; v.u = ((uint32_t)b) << 16;
    return v.f;
}

__device__ __forceinline__ float fast_sigmoid(float x) {
    return 1.f / (1.f + __expf(-x));
}
__device__ __forceinline__ float fast_tanh(float x) {
    return 1.f - 2.f / (__expf(2.f * x) + 1.f);
}

// ---------- cast fp32 -> bf16, 4 elems/thread (weights only) ----------
__global__ __launch_bounds__(256) void cast4_kernel(const float* __restrict__ s,
                                                    unsigned short* __restrict__ d, int n4) {
    int i = blockIdx.x * 256 + threadIdx.x;
    if (i >= n4) return;
    float4 f = ((const float4*)s)[i];
    ushort4 o;
    o.x = f2bf(f.x); o.y = f2bf(f.y); o.z = f2bf(f.z); o.w = f2bf(f.w);
    ((ushort4*)d)[i] = o;
}

// ---------- bias fold + h0 init + counter zero ----------
__global__ __launch_bounds__(256) void init_misc(const float* __restrict__ b_ih,
                                                 const float* __restrict__ b_hh,
                                                 float* __restrict__ bias,
                                                 const float* __restrict__ h0,
                                                 unsigned short* __restrict__ h_ini,
                                                 unsigned int* __restrict__ flags) {
    int i = blockIdx.x * 256 + threadIdx.x;
    if (i < 512) flags[i] = 0u;
    if (i < 4096) bias[i] = b_ih[i] + b_hh[i];
    if (i < 65536) h_ini[i] = f2bf(h0[i]);
}

// ---------- FUSED cooperative kernel: 256 blocks x 512 thr ----------
// blocks 0..127  : wave-autonomous recurrence. Block rb owns 8 channels. Wave (ot,bt)
//                  computes 16 outputs (4ch x 4gates, full K=1024) x 16 batches via one
//                  MFMA tile chain -> all 4 gate pre-acts land in ONE lane's acc regs.
//                  NO LDS, NO reduce, no syncthreads; only s_barrier to aggregate signal.
// blocks 128..255: persistent xW-GEMM producers (r12 structure, stride 128).
template <bool XWF32>
__global__ __launch_bounds__(512, 2) void fused_kernel(
        unsigned short* hb0, unsigned short* hb1,
        void* xw,
        const unsigned short* __restrict__ whh,
        const unsigned short* __restrict__ wih,
        const float* __restrict__ x,
        const float* __restrict__ bias,
        const float* __restrict__ fb,
        const float* __restrict__ c0,
        float* __restrict__ out,
        float* __restrict__ hcout,
        unsigned int* flags) {
    __shared__ __align__(16) char smem[16384];
    const int tid = threadIdx.x;
    const int wave = tid >> 6, lane = tid & 63;
    unsigned int* xwprog = flags + 256;

    if (blockIdx.x >= 128) {
        // ==================== GEMM producer ====================
        unsigned short* As = (unsigned short*)smem;           // 8 KB
        unsigned short* Bs = (unsigned short*)(smem + 8192);  // 8 KB
        const int g = blockIdx.x - 128;                       // 0..127
        const int wm = (wave & 3) * 32, wn = (wave >> 2) * 64;
        const int lr = lane & 15, lk = (lane >> 4) * 8;
        const int r0 = tid >> 2, k0c = (tid & 3) * 8;
        const int rbase = (lane >> 4) * 4;

        for (int tau = g; tau < 8192; tau += 128) {
            const int bm = tau >> 5, bn = tau & 31;
            const int m = bm * 128 + r0;                      // out row = t*64+b
            const float* pax = x + (size_t)((m & 63) * 512 + (m >> 6)) * 1024 + k0c;
            const unsigned short* pbw = wih + (size_t)(bn * 128 + r0) * 1024 + k0c;
            unsigned short* sa = As + r0 * 32 + k0c;
            unsigned short* sb = Bs + r0 * 32 + k0c;

            f32x4 acc[2][4] = {};
            for (int kk = 0; kk < 32; ++kk) {
                const int ko = kk * 32;
                float4 a0 = *(const float4*)(pax + ko);
                float4 a1 = *(const float4*)(pax + ko + 4);
                uint4 bv = *(const uint4*)(pbw + ko);
                __syncthreads();
                ushort4 ca, cb;
                ca.x = f2bf(a0.x); ca.y = f2bf(a0.y); ca.z = f2bf(a0.z); ca.w = f2bf(a0.w);
                cb.x = f2bf(a1.x); cb.y = f2bf(a1.y); cb.z = f2bf(a1.z); cb.w = f2bf(a1.w);
                *(ushort4*)sa = ca;
                *(ushort4*)(sa + 4) = cb;
                *(uint4*)sb = bv;
                __syncthreads();
                short8 af0 = *(const short8*)(As + (wm + lr) * 32 + lk);
                short8 af1 = *(const short8*)(As + (wm + 16 + lr) * 32 + lk);
                short8 bf4[4];
#pragma unroll
                for (int ni = 0; ni < 4; ++ni)
                    bf4[ni] = *(const short8*)(Bs + (wn + ni * 16 + lr) * 32 + lk);
#pragma unroll
                for (int ni = 0; ni < 4; ++ni) {
                    acc[0][ni] = MFMA16(af0, bf4[ni], acc[0][ni]);
                    acc[1][ni] = MFMA16(af1, bf4[ni], acc[1][ni]);
                }
            }
#pragma unroll
            for (int ni = 0; ni < 4; ++ni) {
                const int gc = bn * 128 + wn + ni * 16 + lr;
                const float bvs = bias[gc];
#pragma unroll
                for (int mi = 0; mi < 2; ++mi) {
                    const int gr = bm * 128 + wm + mi * 16 + rbase;
#pragma unroll
                    for (int r = 0; r < 4; ++r) {
                        const float v = acc[mi][ni][r] + bvs;
                        if constexpr (XWF32) {
                            float* p = (float*)xw + (size_t)(gr + r) * 4096 + gc;
                            asm volatile("global_store_dword %0, %1, off sc1"
                                         :: "v"(p), "v"(v) : "memory");
                        } else {
                            unsigned short* p = (unsigned short*)xw + (size_t)(gr + r) * 4096 + gc;
                            const unsigned int hv = f2bf(v);
                            asm volatile("global_store_short %0, %1, off sc1"
                                         :: "v"(p), "v"(hv) : "memory");
                        }
                    }
                }
            }
            asm volatile("s_waitcnt vmcnt(0)" ::: "memory");
            __syncthreads();
            if (tid == 0)
                __hip_atomic_fetch_add(&xwprog[bm], 1u, __ATOMIC_RELAXED,
                                       __HIP_MEMORY_SCOPE_AGENT);
        }
        return;
    }

    // ==================== wave-autonomous recurrence ====================
    const int rb = blockIdx.x, ch0 = rb * 8;
    const int ot = wave >> 2, bt = wave & 3;
    const int lr = lane & 15, g8 = lane >> 4;
    const int ch = ch0 + ot * 4 + g8;        // this lane's channel
    const int batch = bt * 16 + lr;          // this lane's batch
    unsigned int* my_sig = &flags[(rb >> 4) * 32];

    // ---- W_hh: 16 A-rows (r = gate + 4*chansub ordering) x full K -> 32 short8 ----
    short8 Wf[32];
    {
        const unsigned short* wp = whh + (size_t)((lr & 3) * 1024 + ch0 + ot * 4 + (lr >> 2)) * 1024
                                        + g8 * 8;
#pragma unroll
        for (int cc = 0; cc < 8; ++cc) {
            const unsigned short* p = wp + cc * 128;
            asm volatile(
                "global_load_dwordx4 %0, %4, off\n\t"
                "global_load_dwordx4 %1, %4, off offset:64\n\t"
                "global_load_dwordx4 %2, %4, off offset:128\n\t"
                "global_load_dwordx4 %3, %4, off offset:192"
                : "=&v"(Wf[cc * 4]), "=&v"(Wf[cc * 4 + 1]),
                  "=&v"(Wf[cc * 4 + 2]), "=&v"(Wf[cc * 4 + 3])
                : "v"(p));
        }
    }
    asm volatile("s_waitcnt vmcnt(0)" ::: "memory");
    __builtin_amdgcn_sched_barrier(0);

    const float fbv = fb[ch];
    float cr = c0[batch * 1024 + ch];
    const float* xwf = (const float*)xw + (size_t)batch * 4096 + ch;
    const unsigned short* xwb = (const unsigned short*)xw + (size_t)batch * 4096 + ch;
    float* orun = out + (size_t)batch * 524288 + ch;

    // ---- wait for xW slab 0, prefetch xW(t=0) ----
    while (__hip_atomic_load(&xwprog[0], __ATOMIC_RELAXED, __HIP_MEMORY_SCOPE_AGENT) < 32u)
        __builtin_amdgcn_s_sleep(2);
    __builtin_amdgcn_sched_barrier(0);
    float xwv[4];
    {
        uint32_t r0_, r1_, r2_, r3_;
        if constexpr (XWF32) {
            asm volatile(
                "global_load_dword %0, %4, off sc1\n\t"
                "global_load_dword %1, %5, off sc1\n\t"
                "global_load_dword %2, %6, off sc1\n\t"
                "global_load_dword %3, %7, off sc1\n\t"
                "s_waitcnt vmcnt(0)"
                : "=&v"(r0_), "=&v"(r1_), "=&v"(r2_), "=&v"(r3_)
                : "v"(xwf), "v"(xwf + 1024), "v"(xwf + 2048), "v"(xwf + 3072));
            union { uint32_t u; float f; } u0{r0_}, u1{r1_}, u2{r2_}, u3{r3_};
            xwv[0] = u0.f; xwv[1] = u1.f; xwv[2] = u2.f; xwv[3] = u3.f;
        } else {
            asm volatile(
                "global_load_ushort %0, %4, off sc1\n\t"
                "global_load_ushort %1, %5, off sc1\n\t"
                "global_load_ushort %2, %6, off sc1\n\t"
                "global_load_ushort %3, %7, off sc1\n\t"
                "s_waitcnt vmcnt(0)"
                : "=&v"(r0_), "=&v"(r1_), "=&v"(r2_), "=&v"(r3_)
                : "v"(xwb), "v"(xwb + 1024), "v"(xwb + 2048), "v"(xwb + 3072));
            xwv[0] = bf2f((unsigned short)r0_); xwv[1] = bf2f((unsigned short)r1_);
            xwv[2] = bf2f((unsigned short)r2_); xwv[3] = bf2f((unsigned short)r3_);
        }
    }
    __builtin_amdgcn_sched_barrier(0);

    float hv = 0.f;

    for (int t = 0; t < 512; ++t) {
        const unsigned short* hp = (t & 1) ? hb1 : hb0;
        unsigned short* hn       = (t & 1) ? hb0 : hb1;

        // ---- wave0 polls all 8 group counters (each >= 16t); s_barrier releases ----
        if (t > 0) {
            if (wave == 0) {
                const unsigned tgt = 16u * (unsigned)t;
                for (;;) {
                    uint32_t c0_, c1_, c2_, c3_, c4_, c5_, c6_, c7_;
                    asm volatile(
                        "global_load_dword %0, %8, off sc1\n\t"
                        "global_load_dword %1, %8, off offset:128 sc1\n\t"
                        "global_load_dword %2, %8, off offset:256 sc1\n\t"
                        "global_load_dword %3, %8, off offset:384 sc1\n\t"
                        "global_load_dword %4, %8, off offset:512 sc1\n\t"
                        "global_load_dword %5, %8, off offset:640 sc1\n\t"
                        "global_load_dword %6, %8, off offset:768 sc1\n\t"
                        "global_load_dword %7, %8, off offset:896 sc1\n\t"
                        "s_waitcnt vmcnt(0)"
                        : "=&v"(c0_), "=&v"(c1_), "=&v"(c2_), "=&v"(c3_),
                          "=&v"(c4_), "=&v"(c5_), "=&v"(c6_), "=&v"(c7_)
                        : "v"(flags));
                    uint32_t m0 = c0_ < c1_ ? c0_ : c1_;
                    uint32_t m1 = c2_ < c3_ ? c2_ : c3_;
                    uint32_t m2 = c4_ < c5_ ? c4_ : c5_;
                    uint32_t m3 = c6_ < c7_ ? c6_ : c7_;
                    m0 = m0 < m1 ? m0 : m1;
                    m2 = m2 < m3 ? m2 : m3;
                    if ((m0 < m2 ? m0 : m2) >= tgt) break;
                }
            }
            __builtin_amdgcn_sched_barrier(0);
            __builtin_amdgcn_s_barrier();
        }

        // ---- h B-frags: stream 4 chunks of 8 x 16B, pipelined with MFMA ----
        const unsigned short* hb = hp + (size_t)batch * 1024 + g8 * 8;
        short8 af0[8], af1[8];
#define LOAD_CHUNK(BUF, CC)                                                     \
        {                                                                       \
            const unsigned short* p = hb + (CC) * 256;                          \
            asm volatile(                                                       \
                "global_load_dwordx4 %0, %8, off sc1\n\t"                       \
                "global_load_dwordx4 %1, %8, off offset:64 sc1\n\t"             \
                "global_load_dwordx4 %2, %8, off offset:128 sc1\n\t"            \
                "global_load_dwordx4 %3, %8, off offset:192 sc1\n\t"            \
                "global_load_dwordx4 %4, %8, off offset:256 sc1\n\t"            \
                "global_load_dwordx4 %5, %8, off offset:320 sc1\n\t"            \
                "global_load_dwordx4 %6, %8, off offset:384 sc1\n\t"            \
                "global_load_dwordx4 %7, %8, off offset:448 sc1"                \
                : "=&v"(BUF[0]), "=&v"(BUF[1]), "=&v"(BUF[2]), "=&v"(BUF[3]),   \
                  "=&v"(BUF[4]), "=&v"(BUF[5]), "=&v"(BUF[6]), "=&v"(BUF[7])    \
                : "v"(p));                                                      \
        }
        LOAD_CHUNK(af0, 0)
        f32x4 acc0 = {}, acc1 = {};
#pragma unroll
        for (int cc = 0; cc < 4; ++cc) {
            if (cc == 0) { LOAD_CHUNK(af1, 1) }
            else if (cc == 1) { LOAD_CHUNK(af0, 2) }
            else if (cc == 2) { LOAD_CHUNK(af1, 3) }
            if (cc < 3) asm volatile("s_waitcnt vmcnt(8)" ::: "memory");
            else        asm volatile("s_waitcnt vmcnt(0)" ::: "memory");
            __builtin_amdgcn_sched_barrier(0);
#pragma unroll
            for (int j = 0; j < 8; ++j) {
                const short8 a = (cc & 1) ? af1[j] : af0[j];
                if (j & 1) acc1 = MFMA16(Wf[cc * 8 + j], a, acc1);
                else       acc0 = MFMA16(Wf[cc * 8 + j], a, acc0);
            }
        }
#undef LOAD_CHUNK

        // ---- gates: all 4 pre-activations are lane-local ----
        const float lr_ = acc0[0] + acc1[0] + xwv[0];
        const float lf  = acc0[1] + acc1[1] + xwv[1];
        const float lu  = acc0[2] + acc1[2] + xwv[2];
        const float lo  = acc0[3] + acc1[3] + xwv[3];
        const float rg = fast_sigmoid(lr_ - fbv);
        const float fg = fast_sigmoid(lf + fbv);
        const float ug = fast_tanh(lu);
        const float og = fast_sigmoid(lo);
        const float of = 1.f - fg;
        const float gg = rg * (1.f - of * of) + (1.f - rg) * (fg * fg);
        cr = gg * cr + (1.f - gg) * ug;
        hv = og * fast_tanh(cr);

        // ---- h store (sc1), per-wave drain, block signal aggregate ----
        const unsigned hw = (unsigned)f2bf(hv);
        asm volatile("global_store_short %0, %1, off sc1"
                     :: "v"(hn + batch * 1024 + ch), "v"(hw) : "memory");
        asm volatile("s_waitcnt vmcnt(0)" ::: "memory");
        __builtin_amdgcn_sched_barrier(0);
        __builtin_amdgcn_s_barrier();
        if (tid == 0)
            __hip_atomic_fetch_add(my_sig, 1u, __ATOMIC_RELAXED,
                                   __HIP_MEMORY_SCOPE_AGENT);
        __builtin_amdgcn_sched_barrier(0);

        // ---- tail: out store + xW(t+1) readiness + prefetch; drained before next poll ----
        *orun = hv;
        orun += 1024;
        if (t == 511) {
            hcout[batch * 1024 + ch] = hv;
            hcout[65536 + batch * 1024 + ch] = cr;
        }
        {
            const int tp = (t < 511) ? t + 1 : 511;
            if (!(tp & 1)) {
                while (__hip_atomic_load(&xwprog[tp >> 1], __ATOMIC_RELAXED,
                                         __HIP_MEMORY_SCOPE_AGENT) < 32u)
                    __builtin_amdgcn_s_sleep(2);
            }
            uint32_t r0_, r1_, r2_, r3_;
            if constexpr (XWF32) {
                const float* p0 = xwf + (size_t)tp * 262144;
                asm volatile(
                    "global_load_dword %0, %4, off sc1\n\t"
                    "global_load_dword %1, %5, off sc1\n\t"
                    "global_load_dword %2, %6, off sc1\n\t"
                    "global_load_dword %3, %7, off sc1\n\t"
                    "s_waitcnt vmcnt(0)"
                    : "=&v"(r0_), "=&v"(r1_), "=&v"(r2_), "=&v"(r3_)
                    : "v"(p0), "v"(p0 + 1024), "v"(p0 + 2048), "v"(p0 + 3072));
                union { uint32_t u; float f; } u0{r0_}, u1{r1_}, u2{r2_}, u3{r3_};
                xwv[0] = u0.f; xwv[1] = u1.f; xwv[2] = u2.f; xwv[3] = u3.f;
            } else {
                const unsigned short* p0 = xwb + (size_t)tp * 262144;
                asm volatile(
                    "global_load_ushort %0, %4, off sc1\n\t"
                    "global_load_ushort %1, %5, off sc1\n\t"
                    "global_load_ushort %2, %6, off sc1\n\t"
                    "global_load_ushort %3, %7, off sc1\n\t"
                    "s_waitcnt vmcnt(0)"
                    : "=&v"(r0_), "=&v"(r1_), "=&v"(r2_), "=&v"(r3_)
                    : "v"(p0), "v"(p0 + 1024), "v"(p0 + 2048), "v"(p0 + 3072));
                xwv[0] = bf2f((unsigned short)r0_); xwv[1] = bf2f((unsigned short)r1_);
                xwv[2] = bf2f((unsigned short)r2_); xwv[3] = bf2f((unsigned short)r3_);
            }
        }
        asm volatile("s_waitcnt vmcnt(0)" ::: "memory");
        __builtin_amdgcn_sched_barrier(0);
    }
}

extern "C" void kernel_launch(void* const* d_in, const int* in_sizes, int n_in,
                              void* d_out, int out_size, void* d_ws, size_t ws_size,
                              hipStream_t stream) {
    const float* x   = (const float*)d_in[0];
    const float* wih = (const float*)d_in[1];
    const float* bih = (const float*)d_in[2];
    const float* whh = (const float*)d_in[3];
    const float* bhh = (const float*)d_in[4];
    const float* fb  = (const float*)d_in[5];
    const float* h0  = (const float*)d_in[6];
    const float* c0  = (const float*)d_in[7];

    char* ws = (char*)d_ws;
    float* out = (float*)d_out;
    float* hc  = out + 33554432;  // h_n, then c_n

    unsigned short* wihb = (unsigned short*)(ws + OFF_WIH);
    unsigned short* whhb = (unsigned short*)(ws + OFF_WHH);
    float* bias          = (float*)(ws + OFF_BIAS);
    unsigned short* hb0  = (unsigned short*)(ws + OFF_H0);
    unsigned short* hb1  = (unsigned short*)(ws + OFF_H1);
    unsigned int* flags  = (unsigned int*)(ws + OFF_FLG);
    void* xw             = (void*)(ws + OFF_XW);

    const bool f32path = ws_size >= OFF_XW + XW_F32_BYTES;

    cast4_kernel<<<4096, 256, 0, stream>>>(wih, wihb, 1048576);
    cast4_kernel<<<4096, 256, 0, stream>>>(whh, whhb, 1048576);
    init_misc<<<256, 256, 0, stream>>>(bih, bhh, bias, h0, hb0, flags);

    const float* xp = x;
    const float* fbp = fb;
    const float* c0p = c0;
    void* xwp = xw;
    const unsigned short* whhp = whhb;
    const unsigned short* wihp = wihb;
    const float* biasp = bias;
    void* kargs[] = { &hb0, &hb1, &xwp, &whhp, &wihp, &xp, &biasp, &fbp, &c0p,
                      &out, &hc, &flags };
    if (f32path)
        hipLaunchCooperativeKernel((void*)fused_kernel<true>, dim3(256), dim3(512),
                                   kargs, 0, stream);
    else
        hipLaunchCooperativeKernel((void*)fused_kernel<false>, dim3(256), dim3(512),
                                   kargs, 0, stream);
}

// Round 14
// 3692.667 us; speedup vs baseline: 1.3844x; 1.3844x over previous
//
#include <hip/hip_runtime.h>
#include <stdint.h>
#include <stddef.h>

typedef __attribute__((ext_vector_type(8))) short short8;
typedef __attribute__((ext_vector_type(4))) float f32x4;
typedef __attribute__((ext_vector_type(2))) float f32x2;

#define MFMA16(A, B, C) __builtin_amdgcn_mfma_f32_16x16x32_bf16((A), (B), (C), 0, 0, 0)

// ---------- workspace layout (bytes) ----------
static const size_t OFF_WIH  = 67108864;             // w_ih bf16   [4096, 1024]     8388608
static const size_t OFF_WHH  = 75497472;             // w_hh bf16   [4096, 1024]     8388608
static const size_t OFF_BIAS = 83886080;             // b_ih+b_hh   [4096] f32         16384
static const size_t OFF_H0   = 83902464;             // h buf 0 bf16 [64,1024]        131072
static const size_t OFF_H1   = 84033536;             // h buf 1 bf16                  131072
static const size_t OFF_FLG  = 84164608;             // u32[512]: sync ctr[0..255], xwprog[256..511]
static const size_t OFF_XW   = 84426752;             // xW [512*64, 4096] f32 or bf16
static const size_t XW_F32_BYTES = 536870912;

__device__ __forceinline__ unsigned short f2bf(float f) {
    union { float f; uint32_t u; } v; v.f = f;
    uint32_t u = v.u;
    u += 0x7FFFu + ((u >> 16) & 1u);   // round-to-nearest-even
    return (unsigned short)(u >> 16);
}
__device__ __forceinline__ float bf2f(unsigned short b) {
    union { uint32_t u; float f; } v; v.u = ((uint32_t)b) << 16;
    return v.f;
}

__device__ __forceinline__ float fast_sigmoid(float x) {
    return 1.f / (1.f + __expf(-x));
}
__device__ __forceinline__ float fast_tanh(float x) {
    return 1.f - 2.f / (__expf(2.f * x) + 1.f);
}

// ---------- cast fp32 -> bf16, 4 elems/thread (weights only) ----------
__global__ __launch_bounds__(256) void cast4_kernel(const float* __restrict__ s,
                                                    unsigned short* __restrict__ d, int n4) {
    int i = blockIdx.x * 256 + threadIdx.x;
    if (i >= n4) return;
    float4 f = ((const float4*)s)[i];
    ushort4 o;
    o.x = f2bf(f.x); o.y = f2bf(f.y); o.z = f2bf(f.z); o.w = f2bf(f.w);
    ((ushort4*)d)[i] = o;
}

// ---------- bias fold + h0 init + counter zero ----------
__global__ __launch_bounds__(256) void init_misc(const float* __restrict__ b_ih,
                                                 const float* __restrict__ b_hh,
                                                 float* __restrict__ bias,
                                                 const float* __restrict__ h0,
                                                 unsigned short* __restrict__ h_ini,
                                                 unsigned int* __restrict__ flags) {
    int i = blockIdx.x * 256 + threadIdx.x;
    if (i < 512) flags[i] = 0u;
    if (i < 4096) bias[i] = b_ih[i] + b_hh[i];
    if (i < 65536) h_ini[i] = f2bf(h0[i]);
}

// ---------- FUSED cooperative kernel: 256 blocks x 512 thr (round-12 proven best) ----------
// blocks 0..63   : round-10 persistent recurrence (K-split-8, transposed MFMA, b128
//                  swizzled partials, split-phase dataflow counters; xW via sc1 asm +
//                  per-bm readiness poll folded into the tail prefetch).
// blocks 64..255 : persistent xW-GEMM producers. Tiles 128x128, t-ordered round-robin.
//                  x cast f32->bf16 in-register during staging. sc1 stores (write-through
//                  L3); after vmcnt(0)+barrier, tid0 bumps xwprog[bm] (32 tiles per bm).
template <bool XWF32>
__global__ __launch_bounds__(512, 2) void fused_kernel(
        unsigned short* hb0, unsigned short* hb1,
        void* xw,
        const unsigned short* __restrict__ whh,
        const unsigned short* __restrict__ wih,
        const float* __restrict__ x,
        const float* __restrict__ bias,
        const float* __restrict__ fb,
        const float* __restrict__ c0,
        float* __restrict__ out,
        float* __restrict__ hcout,
        unsigned int* flags) {
    __shared__ __align__(16) char smem[131072];
    const int tid = threadIdx.x;
    const int wave = tid >> 6, lane = tid & 63;
    unsigned int* xwprog = flags + 256;

    if (blockIdx.x >= 64) {
        // ==================== GEMM producer ====================
        unsigned short* As = (unsigned short*)smem;           // 8 KB
        unsigned short* Bs = (unsigned short*)(smem + 8192);  // 8 KB
        const int g = blockIdx.x - 64;                        // 0..191
        const int wm = (wave & 3) * 32, wn = (wave >> 2) * 64;
        const int lr = lane & 15, lk = (lane >> 4) * 8;
        const int r0 = tid >> 2, k0c = (tid & 3) * 8;
        const int rbase = (lane >> 4) * 4;

        for (int tau = g; tau < 8192; tau += 192) {
            const int bm = tau >> 5, bn = tau & 31;
            const int m = bm * 128 + r0;                      // out row = t*64+b
            const float* pax = x + (size_t)((m & 63) * 512 + (m >> 6)) * 1024 + k0c;
            const unsigned short* pbw = wih + (size_t)(bn * 128 + r0) * 1024 + k0c;
            unsigned short* sa = As + r0 * 32 + k0c;
            unsigned short* sb = Bs + r0 * 32 + k0c;

            f32x4 acc[2][4] = {};
            for (int kk = 0; kk < 32; ++kk) {
                const int ko = kk * 32;
                float4 a0 = *(const float4*)(pax + ko);
                float4 a1 = *(const float4*)(pax + ko + 4);
                uint4 bv = *(const uint4*)(pbw + ko);
                __syncthreads();
                ushort4 ca, cb;
                ca.x = f2bf(a0.x); ca.y = f2bf(a0.y); ca.z = f2bf(a0.z); ca.w = f2bf(a0.w);
                cb.x = f2bf(a1.x); cb.y = f2bf(a1.y); cb.z = f2bf(a1.z); cb.w = f2bf(a1.w);
                *(ushort4*)sa = ca;
                *(ushort4*)(sa + 4) = cb;
                *(uint4*)sb = bv;
                __syncthreads();
                short8 af0 = *(const short8*)(As + (wm + lr) * 32 + lk);
                short8 af1 = *(const short8*)(As + (wm + 16 + lr) * 32 + lk);
                short8 bf4[4];
#pragma unroll
                for (int ni = 0; ni < 4; ++ni)
                    bf4[ni] = *(const short8*)(Bs + (wn + ni * 16 + lr) * 32 + lk);
#pragma unroll
                for (int ni = 0; ni < 4; ++ni) {
                    acc[0][ni] = MFMA16(af0, bf4[ni], acc[0][ni]);
                    acc[1][ni] = MFMA16(af1, bf4[ni], acc[1][ni]);
                }
            }
            // epilogue: bias + sc1 stores (write-through to L3)
#pragma unroll
            for (int ni = 0; ni < 4; ++ni) {
                const int gc = bn * 128 + wn + ni * 16 + lr;
                const float bvs = bias[gc];
#pragma unroll
                for (int mi = 0; mi < 2; ++mi) {
                    const int gr = bm * 128 + wm + mi * 16 + rbase;
#pragma unroll
                    for (int r = 0; r < 4; ++r) {
                        const float v = acc[mi][ni][r] + bvs;
                        if constexpr (XWF32) {
                            float* p = (float*)xw + (size_t)(gr + r) * 4096 + gc;
                            asm volatile("global_store_dword %0, %1, off sc1"
                                         :: "v"(p), "v"(v) : "memory");
                        } else {
                            unsigned short* p = (unsigned short*)xw + (size_t)(gr + r) * 4096 + gc;
                            const unsigned int hv = f2bf(v);
                            asm volatile("global_store_short %0, %1, off sc1"
                                         :: "v"(p), "v"(hv) : "memory");
                        }
                    }
                }
            }
            asm volatile("s_waitcnt vmcnt(0)" ::: "memory");   // stores at L3
            __syncthreads();
            if (tid == 0)
                __hip_atomic_fetch_add(&xwprog[bm], 1u, __ATOMIC_RELAXED,
                                       __HIP_MEMORY_SCOPE_AGENT);
        }
        return;
    }

    // ==================== recurrence consumer (round-10 structure) ====================
    float* part = (float*)smem;                       // [kq][batch][out] 131072 B
    const int bk = blockIdx.x, ch0 = bk * 16;
    const int kq = wave;                              // K-slice owner
    const int lr = lane & 15, g = lane >> 4;
    unsigned int* ctr = flags;

    // ---- W_hh fragments -> registers, once ----
    short8 Wf[4][4];
#pragma unroll
    for (int ni = 0; ni < 4; ++ni)
#pragma unroll
        for (int ks = 0; ks < 4; ++ks) {
            const unsigned short* p = whh + (size_t)(ni * 1024 + ch0 + lr) * 1024
                                          + kq * 128 + ks * 32 + g * 8;
            asm volatile("global_load_dwordx4 %0, %1, off"
                         : "=&v"(Wf[ni][ks]) : "v"(p));
        }
    asm volatile("s_waitcnt vmcnt(0)" ::: "memory");
    __builtin_amdgcn_sched_barrier(0);

    // ---- per-thread epilogue map ----
    const int b  = tid >> 3;
    const int j0 = 2 * (tid & 7);
    const int ch = ch0 + j0;
    const float fb0 = fb[ch], fb1 = fb[ch + 1];
    float c0r = c0[b * 1024 + ch], c1r = c0[b * 1024 + ch + 1];

    // ---- loop-invariant LDS indices (round-8 verified swizzle) ----
    int wsl[4];
#pragma unroll
    for (int oi = 0; oi < 4; ++oi)
        wsl[oi] = kq * 4096 + lr * 64 + (((oi * 4 + g) ^ (lr & 7)) * 4);
    int rsl[4];
#pragma unroll
    for (int g4 = 0; g4 < 4; ++g4)
        rsl[g4] = b * 64 + (((g4 * 4 + (j0 >> 2)) ^ (b & 7)) * 4) + (j0 & 3);

    // ---- pointers / sync addresses ----
    const float* xwf = (const float*)xw + (size_t)b * 4096 + ch;
    const unsigned short* xwb = (const unsigned short*)xw + (size_t)b * 4096 + ch;
    float* orun = out + (size_t)b * 524288 + ch;
    unsigned int* my_sig  = &ctr[(bk >> 3) * 32];
    unsigned int* my_poll = &ctr[kq * 32];

    // ---- wait for xW(t=0) (bm 0 complete), then sc1 prefetch ----
    {
        const unsigned int* pr0 = &xwprog[0];
        while (__hip_atomic_load(pr0, __ATOMIC_RELAXED, __HIP_MEMORY_SCOPE_AGENT) < 32u) {}
    }
    __builtin_amdgcn_sched_barrier(0);
    f32x2 xf[4];
    uint32_t xu[4];
    if constexpr (XWF32) {
        asm volatile(
            "global_load_dwordx2 %0, %4, off sc1\n\t"
            "global_load_dwordx2 %1, %5, off sc1\n\t"
            "global_load_dwordx2 %2, %6, off sc1\n\t"
            "global_load_dwordx2 %3, %7, off sc1"
            : "=&v"(xf[0]), "=&v"(xf[1]), "=&v"(xf[2]), "=&v"(xf[3])
            : "v"(xwf), "v"(xwf + 1024), "v"(xwf + 2048), "v"(xwf + 3072));
    } else {
        asm volatile(
            "global_load_dword %0, %4, off sc1\n\t"
            "global_load_dword %1, %5, off sc1\n\t"
            "global_load_dword %2, %6, off sc1\n\t"
            "global_load_dword %3, %7, off sc1"
            : "=&v"(xu[0]), "=&v"(xu[1]), "=&v"(xu[2]), "=&v"(xu[3])
            : "v"(xwb), "v"(xwb + 1024), "v"(xwb + 2048), "v"(xwb + 3072));
    }
    asm volatile("s_waitcnt vmcnt(0)" ::: "memory");
    __builtin_amdgcn_sched_barrier(0);

    float h0v = 0.f, h1v = 0.f;

    for (int t = 0; t < 512; ++t) {
        const unsigned short* hp = (t & 1) ? hb1 : hb0;
        unsigned short* hn       = (t & 1) ? hb0 : hb1;

        // ---- per-wave poll: only MY K-slice's 8 producers ----
        if (t > 0) {
            const unsigned tgt = (unsigned)t * 8u;
            while (__hip_atomic_load(my_poll, __ATOMIC_RELAXED,
                                     __HIP_MEMORY_SCOPE_AGENT) < tgt) {}
        }
        __builtin_amdgcn_sched_barrier(0);

        // ---- 16 PARALLEL h sc1 loads ----
        short8 af[4][4];
        {
            const unsigned short* hbase = hp + (size_t)lr * 1024 + kq * 128 + g * 8;
#pragma unroll
            for (int bi = 0; bi < 4; ++bi) {
                const unsigned short* p = hbase + (size_t)bi * 16 * 1024;
                asm volatile(
                    "global_load_dwordx4 %0, %4, off sc1\n\t"
                    "global_load_dwordx4 %1, %4, off offset:64 sc1\n\t"
                    "global_load_dwordx4 %2, %4, off offset:128 sc1\n\t"
                    "global_load_dwordx4 %3, %4, off offset:192 sc1"
                    : "=&v"(af[bi][0]), "=&v"(af[bi][1]),
                      "=&v"(af[bi][2]), "=&v"(af[bi][3])
                    : "v"(p));
            }
        }
        asm volatile("s_waitcnt vmcnt(0)" ::: "memory");
        __builtin_amdgcn_sched_barrier(0);

        // ---- 64 MFMA, transposed: D rows = outputs, cols = batch ----
        f32x4 acc[4][4] = {};
#pragma unroll
        for (int ks = 0; ks < 4; ++ks)
#pragma unroll
            for (int oi = 0; oi < 4; ++oi)
#pragma unroll
                for (int bi = 0; bi < 4; ++bi)
                    acc[oi][bi] = MFMA16(Wf[oi][ks], af[bi][ks], acc[oi][bi]);

        // ---- partials: 16 x ds_write_b128, swizzled ----
#pragma unroll
        for (int oi = 0; oi < 4; ++oi)
#pragma unroll
            for (int bi = 0; bi < 4; ++bi)
                *(f32x4*)&part[wsl[oi] + bi * 1024] = acc[oi][bi];
        __syncthreads();

        // ---- 8-way K-reduce + gates + state update ----
        float l0[4], l1[4];
#pragma unroll
        for (int g4 = 0; g4 < 4; ++g4) {
            float s0, s1;
            if constexpr (XWF32) { s0 = xf[g4].x; s1 = xf[g4].y; }
            else { s0 = bf2f((unsigned short)xu[g4]);
                   s1 = bf2f((unsigned short)(xu[g4] >> 16)); }
#pragma unroll
            for (int k8 = 0; k8 < 8; ++k8) {
                const float2 v = *(const float2*)&part[k8 * 4096 + rsl[g4]];
                s0 += v.x; s1 += v.y;
            }
            l0[g4] = s0; l1[g4] = s1;
        }
        const float rg0 = fast_sigmoid(l0[0] - fb0);
        const float fg0 = fast_sigmoid(l0[1] + fb0);
        const float ug0 = fast_tanh(l0[2]);
        const float og0 = fast_sigmoid(l0[3]);
        const float rg1 = fast_sigmoid(l1[0] - fb1);
        const float fg1 = fast_sigmoid(l1[1] + fb1);
        const float ug1 = fast_tanh(l1[2]);
        const float og1 = fast_sigmoid(l1[3]);
        const float of0 = 1.f - fg0, of1 = 1.f - fg1;
        const float gg0 = rg0 * (1.f - of0 * of0) + (1.f - rg0) * (fg0 * fg0);
        const float gg1 = rg1 * (1.f - of1 * of1) + (1.f - rg1) * (fg1 * fg1);
        c0r = gg0 * c0r + (1.f - gg0) * ug0;
        c1r = gg1 * c1r + (1.f - gg1) * ug1;
        h0v = og0 * fast_tanh(c0r);
        h1v = og1 * fast_tanh(c1r);

        // h (cross-block): one u32 agent-scope store -> straight to L3
        const unsigned hw = ((unsigned)f2bf(h1v) << 16) | (unsigned)f2bf(h0v);
        __hip_atomic_store((unsigned int*)&hn[b * 1024 + ch], hw,
                           __ATOMIC_RELAXED, __HIP_MEMORY_SCOPE_AGENT);

        // ---- drain h stores block-wide, then signal my group's counter ----
        __syncthreads();
        if (tid == 0)
            __hip_atomic_fetch_add(my_sig, 1u, __ATOMIC_RELAXED,
                                   __HIP_MEMORY_SCOPE_AGENT);
        __builtin_amdgcn_sched_barrier(0);

        // ---- post-signal tail: out store + xW(t+1) readiness + sc1 prefetch ----
        *(f32x2*)orun = (f32x2){h0v, h1v};
        orun += 1024;
        {
            const int tp = (t < 511) ? t + 1 : 511;
            if (!(tp & 1)) {   // new bm slab: ensure producers finished it
                const unsigned int* pr = &xwprog[tp >> 1];
                while (__hip_atomic_load(pr, __ATOMIC_RELAXED,
                                         __HIP_MEMORY_SCOPE_AGENT) < 32u) {}
            }
            if constexpr (XWF32) {
                const float* p0 = xwf + (size_t)tp * 262144;
                asm volatile(
                    "global_load_dwordx2 %0, %4, off sc1\n\t"
                    "global_load_dwordx2 %1, %5, off sc1\n\t"
                    "global_load_dwordx2 %2, %6, off sc1\n\t"
                    "global_load_dwordx2 %3, %7, off sc1"
                    : "=&v"(xf[0]), "=&v"(xf[1]), "=&v"(xf[2]), "=&v"(xf[3])
                    : "v"(p0), "v"(p0 + 1024), "v"(p0 + 2048), "v"(p0 + 3072));
            } else {
                const unsigned short* p0 = xwb + (size_t)tp * 262144;
                asm volatile(
                    "global_load_dword %0, %4, off sc1\n\t"
                    "global_load_dword %1, %5, off sc1\n\t"
                    "global_load_dword %2, %6, off sc1\n\t"
                    "global_load_dword %3, %7, off sc1"
                    : "=&v"(xu[0]), "=&v"(xu[1]), "=&v"(xu[2]), "=&v"(xu[3])
                    : "v"(p0), "v"(p0 + 1024), "v"(p0 + 2048), "v"(p0 + 3072));
            }
        }
        asm volatile("s_waitcnt vmcnt(0)" ::: "memory");   // tail drain
        __builtin_amdgcn_sched_barrier(0);
    }

    *(f32x2*)&hcout[b * 1024 + ch] = (f32x2){h0v, h1v};
    *(f32x2*)&hcout[65536 + b * 1024 + ch] = (f32x2){c0r, c1r};
}

extern "C" void kernel_launch(void* const* d_in, const int* in_sizes, int n_in,
                              void* d_out, int out_size, void* d_ws, size_t ws_size,
                              hipStream_t stream) {
    const float* x   = (const float*)d_in[0];
    const float* wih = (const float*)d_in[1];
    const float* bih = (const float*)d_in[2];
    const float* whh = (const float*)d_in[3];
    const float* bhh = (const float*)d_in[4];
    const float* fb  = (const float*)d_in[5];
    const float* h0  = (const float*)d_in[6];
    const float* c0  = (const float*)d_in[7];

    char* ws = (char*)d_ws;
    float* out = (float*)d_out;
    float* hc  = out + 33554432;  // h_n, then c_n

    unsigned short* wihb = (unsigned short*)(ws + OFF_WIH);
    unsigned short* whhb = (unsigned short*)(ws + OFF_WHH);
    float* bias          = (float*)(ws + OFF_BIAS);
    unsigned short* hb0  = (unsigned short*)(ws + OFF_H0);
    unsigned short* hb1  = (unsigned short*)(ws + OFF_H1);
    unsigned int* flags  = (unsigned int*)(ws + OFF_FLG);
    void* xw             = (void*)(ws + OFF_XW);

    const bool f32path = ws_size >= OFF_XW + XW_F32_BYTES;

    cast4_kernel<<<4096, 256, 0, stream>>>(wih, wihb, 1048576);
    cast4_kernel<<<4096, 256, 0, stream>>>(whh, whhb, 1048576);
    init_misc<<<256, 256, 0, stream>>>(bih, bhh, bias, h0, hb0, flags);

    const float* xp = x;
    const float* fbp = fb;
    const float* c0p = c0;
    void* xwp = xw;
    const unsigned short* whhp = whhb;
    const unsigned short* wihp = wihb;
    const float* biasp = bias;
    void* kargs[] = { &hb0, &hb1, &xwp, &whhp, &wihp, &xp, &biasp, &fbp, &c0p,
                      &out, &hc, &flags };
    if (f32path)
        hipLaunchCooperativeKernel((void*)fused_kernel<true>, dim3(256), dim3(512),
                                   kargs, 0, stream);
    else
        hipLaunchCooperativeKernel((void*)fused_kernel<false>, dim3(256), dim3(512),
                                   kargs, 0, stream);
}